// Round 18
// baseline (1470.458 us; speedup 1.0000x reference)
//
#include <hip/hip_runtime.h>
#include <math.h>

#define D   32
#define FIN 16
#define KH  128
#define NW  1024
#define NKT 9          // 8 real K-tiles + 1 bias tile (K=144, ones-column ⊗ b2-row)
#define WEPITCH 1032   // shorts per WeL edge row (1024 + 8 pad)

typedef __attribute__((ext_vector_type(8)))  short short8;
typedef __attribute__((ext_vector_type(16))) float f32x16;

__device__ __forceinline__ float sigf(float x){ return 1.0f/(1.0f+expf(-x)); }
__device__ __forceinline__ short f2bf(float f){ __bf16 h = (__bf16)f; return __builtin_bit_cast(short, h); }
__device__ __forceinline__ float bf2f(short s){ return (float)__builtin_bit_cast(__bf16, s); }

// ---------------- degree / inv_deg ----------------
__global__ void k_deg(const int* __restrict__ dst, int* __restrict__ deg, int E){
    int e = blockIdx.x*256 + threadIdx.x;
    if (e < E) atomicAdd(&deg[dst[e]], 1);
}
__global__ void k_invdeg(const int* __restrict__ deg, float* __restrict__ invd, int n){
    int i = blockIdx.x*256 + threadIdx.x;
    if (i < n) { int d = deg[i]; invd[i] = (d > 0) ? (1.0f/(float)d) : 0.0f; }
}

// ---------------- transpose LSTM / lin1 weights ----------------
__global__ void k_tposew(const float* __restrict__ wih, const float* __restrict__ whh,
                         const float* __restrict__ l1w,
                         float* __restrict__ wihT, float* __restrict__ whhT,
                         float* __restrict__ l1T){
    int t = blockIdx.x*256 + threadIdx.x;
    if (t < 128*64) { int j = t/64, i = t%64; wihT[i*128+j] = wih[t]; l1T[i*128+j] = l1w[t]; }
    if (t < 128*32) { int j = t/32, i = t%32; whhT[i*128+j] = whh[t]; }
}

// ---------------- lin0 + relu (fp32) ----------------
__global__ __launch_bounds__(256) void k_lin0(const float* __restrict__ x,
    const float* __restrict__ w, const float* __restrict__ b,
    float* __restrict__ out, int n){
    __shared__ float wT[FIN*33];
    __shared__ float sb[D];
    int t = threadIdx.x;
    for (int idx = t; idx < D*FIN; idx += 256) {
        int o = idx/FIN, i = idx%FIN; wT[i*33+o] = w[idx];
    }
    if (t < D) sb[t] = b[t];
    __syncthreads();
    int g = t >> 5, o = t & 31;
    int node = blockIdx.x*8 + g;
    if (node >= n) return;
    float xo = (o < FIN) ? x[node*FIN + o] : 0.0f;
    float acc = sb[o];
    #pragma unroll
    for (int i = 0; i < FIN; ++i) {
        float xi = __shfl(xo, i, 32);
        acc += xi * wT[i*33+o];
    }
    out[node*D + o] = fmaxf(acc, 0.0f);
}

// ---------------- ehid in MFMA-fragment-major bf16, K extended to 144 ----------------
__global__ __launch_bounds__(256) void k_ehidf(const float* __restrict__ attr,
    const float* __restrict__ w1, const float* __restrict__ b1,
    short* __restrict__ ehidF, int E, int nte){
    int f = blockIdx.x*256 + threadIdx.x;
    if (f >= nte*NKT*64) return;
    int l = f & 63; int g = f >> 6; int kt = g % NKT; int te = g / NKT;
    int e = te*32 + (l & 31);
    int hi = l >> 5;
    short8 v;
    if (kt == 8) {
        #pragma unroll
        for (int j = 0; j < 8; ++j) v[j] = 0;
        if (hi == 0) v[0] = f2bf(1.0f);
    } else {
        int k0 = kt*16 + hi*8;
        float a0=0.f, a1=0.f, a2=0.f;
        if (e < E) { a0 = attr[(size_t)e*3]; a1 = attr[(size_t)e*3+1]; a2 = attr[(size_t)e*3+2]; }
        #pragma unroll
        for (int j = 0; j < 8; ++j) {
            int k = k0 + j;
            float t = b1[k] + a0*w1[k*3] + a1*w1[k*3+1] + a2*w1[k*3+2];
            v[j] = f2bf(fmaxf(t, 0.0f));
        }
    }
    *reinterpret_cast<short8*>(ehidF + (size_t)f*8) = v;
}

// ---------------- w2 in MFMA-fragment-major bf16 (B operand), K=144 ----------------
__global__ __launch_bounds__(256) void k_w2f(const float* __restrict__ w2,
    const float* __restrict__ b2, short* __restrict__ w2F){
    int f = blockIdx.x*256 + threadIdx.x;
    if (f >= 32*NKT*64) return;
    int l = f & 63; int g = f >> 6; int kt = g % NKT; int tn = g / NKT;
    int n = tn*32 + (l & 31);
    int hi = l >> 5;
    short8 v;
    if (kt == 8) {
        #pragma unroll
        for (int j = 0; j < 8; ++j) v[j] = 0;
        if (hi == 0) v[0] = f2bf(b2[n]);
    } else {
        int k0 = kt*16 + hi*8;
        #pragma unroll
        for (int j = 0; j < 8; ++j) v[j] = f2bf(w2[n*KH + k0 + j]);
    }
    *reinterpret_cast<short8*>(w2F + (size_t)f*8) = v;
}

// ---------------- fused NNConv (R4 structure, measured 178 us): MFMA -> bf16 WeL -> shfl msg ----
// Block = 32-edge tile, 16 waves. Wave w: mfma(A=ehfrag, B=w2frag(nt)), nt∈{2w,2w+1}
//   -> C[row=edge=(r&3)+8(r>>2)+4hi][col], n = nt*32+col. Store bf16 to WeL[edge][n].
// msg phase: wave w handles edges 2w+hi; lane col computes sum_i x[src][i]*WeL[edge][i*32+col]
// via 32x {shfl broadcast + ds_read_u16 + fma}; ONE atomic per (edge,o), half-wave coalesced.
// Bias b2 enters via the NKT=9 K-extension (ones-column ⊗ b2-row) — no epilogue add needed.
__global__ __launch_bounds__(1024) void k_fused(
    const short* __restrict__ ehidF, const short* __restrict__ w2F,
    const float* __restrict__ nodef,
    const int* __restrict__ src, const int* __restrict__ dst,
    float* __restrict__ agg){
    __shared__ short WeL[32*WEPITCH];     // 66048 B, pitch 1032 breaks bank alias
    int tid = threadIdx.x;
    int w = tid >> 6, l = tid & 63;
    int te = blockIdx.x;                  // E % 32 == 0
    int col = l & 31, hi = l >> 5;

    int nt0 = 2*w, nt1 = 2*w + 1;
    const short8* A8 = reinterpret_cast<const short8*>(ehidF) + (size_t)te*(NKT*64);
    const short8* B8 = reinterpret_cast<const short8*>(w2F);
    f32x16 acc0 = {}; f32x16 acc1 = {};
    #pragma unroll
    for (int kt = 0; kt < NKT; ++kt) {
        short8 a  = A8[kt*64 + l];
        short8 b0 = B8[(nt0*NKT + kt)*64 + l];
        short8 b1 = B8[(nt1*NKT + kt)*64 + l];
        acc0 = __builtin_amdgcn_mfma_f32_32x32x16_bf16(a, b0, acc0, 0, 0, 0);
        acc1 = __builtin_amdgcn_mfma_f32_32x32x16_bf16(a, b1, acc1, 0, 0, 0);
    }
    #pragma unroll
    for (int r = 0; r < 16; ++r) {
        int edge = (r & 3) + 8*(r >> 2) + 4*hi;
        WeL[edge*WEPITCH + nt0*32 + col] = f2bf(acc0[r]);
        WeL[edge*WEPITCH + nt1*32 + col] = f2bf(acc1[r]);
    }
    __syncthreads();

    // msg phase: edge eloc = 2w + hi, lane handles output o = col
    int eloc = 2*w + hi;
    int e = te*32 + eloc;
    int s = src[e];
    float vo = nodef[(size_t)s*D + col];
    float msg = 0.0f;
    const short* W = &WeL[eloc*WEPITCH];
    #pragma unroll
    for (int i = 0; i < D; ++i) {
        float vi = __shfl(vo, i, 32);
        msg += vi * bf2f(W[i*32 + col]);
    }
    atomicAdd(&agg[(size_t)dst[e]*D + col], msg);
}

// ---------------- scatter-mean finish + root + relu + GRU v4 (2-node weight-read batching) ----
// Per q-step the 6 gate-weight float4 are read ONCE and applied to 2 nodes -> per-node LDS
// b128 drops ~80 -> ~52. FMA order per node identical to v2 -> bit-identical numerics.
// Register budget (R15 lesson, x1.5 pessimism): ~68 nominal -> <=~105, under the 128 cap
// that launch_bounds(256,2) grants (measured R12/R15).
__global__ __launch_bounds__(256, 2) void k_gru(float* __restrict__ out,
    float* __restrict__ agg, const float* __restrict__ invd,
    const float* __restrict__ root_w, const float* __restrict__ conv_b,
    const float* __restrict__ wih, const float* __restrict__ whh,
    const float* __restrict__ bih, const float* __restrict__ bhh, int n){
    __shared__ float swih[3][32][36];   // swih[c][o][i] = wih[(c*32+o)*32+i]
    __shared__ float swhh[3][32][36];
    __shared__ float srt[32][36];       // srt[o][i] = root_w[i*32+o]
    __shared__ float hL[16][32], mL[16][32];
    __shared__ float sbih[96], sbhh[96], scb[32];
    int t = threadIdx.x;
    for (int idx = t; idx < 96*32; idx += 256) {
        int j = idx >> 5, i = idx & 31; int c = j >> 5, o = j & 31;
        swih[c][o][i] = wih[idx];
        swhh[c][o][i] = whh[idx];
    }
    for (int idx = t; idx < 32*32; idx += 256) {
        int i = idx >> 5, o = idx & 31;
        srt[o][i] = root_w[idx];
    }
    if (t < 96) { sbih[t] = bih[t]; sbhh[t] = bhh[t]; }
    if (t < 32) scb[t] = conv_b[t];
    __syncthreads();

    int g = t >> 5, o = t & 31;         // 8 groups x 32 lanes; group handles nodes 2g, 2g+1
    int npass = (n + 15) / 16;          // 16 nodes per block-pass
    for (int p = blockIdx.x; p < npass; p += gridDim.x) {
        int n0 = p*16 + g*2, n1 = n0 + 1;
        float ho0 = 0.0f, ho1 = 0.0f, am0, am1;
        {
            float a0 = 0.0f, a1 = 0.0f, iv0 = 0.0f, iv1 = 0.0f;
            if (n0 < n) {
                ho0 = out[(size_t)n0*D + o];
                a0  = agg[(size_t)n0*D + o];
                agg[(size_t)n0*D + o] = 0.0f;          // pre-zero for next iteration
                iv0 = invd[n0];
            }
            if (n1 < n) {
                ho1 = out[(size_t)n1*D + o];
                a1  = agg[(size_t)n1*D + o];
                agg[(size_t)n1*D + o] = 0.0f;
                iv1 = invd[n1];
            }
            hL[g*2][o]   = ho0;                        // in-wave producer/consumer
            hL[g*2+1][o] = ho1;
            am0 = a0*iv0 + scb[o];
            am1 = a1*iv1 + scb[o];
        }
        // root matvec: am += sum_i h[node][i] * root_w[i][o]; weights read once per q
        #pragma unroll
        for (int q = 0; q < 8; ++q) {
            float4 r4  = *reinterpret_cast<const float4*>(&srt[o][q*4]);
            float4 h4a = *reinterpret_cast<const float4*>(&hL[g*2][q*4]);    // broadcast
            float4 h4b = *reinterpret_cast<const float4*>(&hL[g*2+1][q*4]);
            am0 += h4a.x*r4.x + h4a.y*r4.y + h4a.z*r4.z + h4a.w*r4.w;
            am1 += h4b.x*r4.x + h4b.y*r4.y + h4b.z*r4.z + h4b.w*r4.w;
        }
        float m0 = fmaxf(am0, 0.0f), m1 = fmaxf(am1, 0.0f);
        mL[g*2][o]   = m0;
        mL[g*2+1][o] = m1;
        float gi0a = sbih[o], gi1a = sbih[o+32], gi2a = sbih[o+64];
        float gh0a = sbhh[o], gh1a = sbhh[o+32], gh2a = sbhh[o+64];
        float gi0b = gi0a, gi1b = gi1a, gi2b = gi2a;
        float gh0b = gh0a, gh1b = gh1a, gh2b = gh2a;
        #pragma unroll
        for (int q = 0; q < 8; ++q) {
            float4 wa = *reinterpret_cast<const float4*>(&swih[0][o][q*4]);
            float4 wb = *reinterpret_cast<const float4*>(&swih[1][o][q*4]);
            float4 wc = *reinterpret_cast<const float4*>(&swih[2][o][q*4]);
            float4 va = *reinterpret_cast<const float4*>(&swhh[0][o][q*4]);
            float4 vb = *reinterpret_cast<const float4*>(&swhh[1][o][q*4]);
            float4 vc = *reinterpret_cast<const float4*>(&swhh[2][o][q*4]);
            float4 m4a = *reinterpret_cast<const float4*>(&mL[g*2][q*4]);    // broadcast
            float4 h4a = *reinterpret_cast<const float4*>(&hL[g*2][q*4]);
            gi0a += m4a.x*wa.x + m4a.y*wa.y + m4a.z*wa.z + m4a.w*wa.w;
            gi1a += m4a.x*wb.x + m4a.y*wb.y + m4a.z*wb.z + m4a.w*wb.w;
            gi2a += m4a.x*wc.x + m4a.y*wc.y + m4a.z*wc.z + m4a.w*wc.w;
            gh0a += h4a.x*va.x + h4a.y*va.y + h4a.z*va.z + h4a.w*va.w;
            gh1a += h4a.x*vb.x + h4a.y*vb.y + h4a.z*vb.z + h4a.w*vb.w;
            gh2a += h4a.x*vc.x + h4a.y*vc.y + h4a.z*vc.z + h4a.w*vc.w;
            float4 m4b = *reinterpret_cast<const float4*>(&mL[g*2+1][q*4]);
            float4 h4b = *reinterpret_cast<const float4*>(&hL[g*2+1][q*4]);
            gi0b += m4b.x*wa.x + m4b.y*wa.y + m4b.z*wa.z + m4b.w*wa.w;
            gi1b += m4b.x*wb.x + m4b.y*wb.y + m4b.z*wb.z + m4b.w*wb.w;
            gi2b += m4b.x*wc.x + m4b.y*wc.y + m4b.z*wc.z + m4b.w*wc.w;
            gh0b += h4b.x*va.x + h4b.y*va.y + h4b.z*va.z + h4b.w*va.w;
            gh1b += h4b.x*vb.x + h4b.y*vb.y + h4b.z*vb.z + h4b.w*vb.w;
            gh2b += h4b.x*vc.x + h4b.y*vc.y + h4b.z*vc.z + h4b.w*vc.w;
        }
        if (n0 < n) {
            float r  = sigf(gi0a+gh0a);
            float z  = sigf(gi1a+gh1a);
            float ng = tanhf(gi2a + r*gh2a);
            out[(size_t)n0*D + o] = (1.0f - z)*ng + z*ho0;
        }
        if (n1 < n) {
            float r  = sigf(gi0b+gh0b);
            float z  = sigf(gi1b+gh1b);
            float ng = tanhf(gi2b + r*gh2b);
            out[(size_t)n1*D + o] = (1.0f - z)*ng + z*ho1;
        }
    }
}

// ---------------- Set2Set (3 steps) + lin1/lin2 readout (fp32, wave-parallel) ----------------
__global__ __launch_bounds__(64) void k_s2s(const float* __restrict__ out,
    const float* __restrict__ wihT, const float* __restrict__ whhT,
    const float* __restrict__ bih, const float* __restrict__ bhh,
    const float* __restrict__ l1T, const float* __restrict__ l1b,
    const float* __restrict__ l2w, const float* __restrict__ l2b,
    float* __restrict__ dpred, float* __restrict__ demb, int n, int ngr){
    int b = blockIdx.x, t = threadIdx.x;
    int start = (int)(((long long)b*n + ngr - 1)/ngr);
    int end   = (int)(((long long)(b+1)*n + ngr - 1)/ngr);
    if (end > n) end = n;
    int cnt = end - start;              // 24 or 25 here
    __shared__ float oL[32][33];
    __shared__ float qs[2*D];
    __shared__ float hhv[D], ccv[D], qv[D];
    __shared__ float gate[4*D];
    __shared__ float ea[32];
    for (int idx = t; idx < cnt*D; idx += 64) {
        int r = idx >> 5, o = idx & 31;
        oL[r][o] = out[(size_t)(start+r)*D + o];
    }
    if (t < 2*D) qs[t] = 0.0f;
    if (t < D) { hhv[t] = 0.0f; ccv[t] = 0.0f; }
    __syncthreads();
    for (int step = 0; step < 3; ++step) {
        float g1 = bih[t] + bhh[t];
        float g2 = bih[t+64] + bhh[t+64];
        #pragma unroll
        for (int i = 0; i < 2*D; ++i) {
            float q = qs[i];
            g1 += q * wihT[i*128 + t];
            g2 += q * wihT[i*128 + t + 64];
        }
        #pragma unroll
        for (int i = 0; i < D; ++i) {
            float h = hhv[i];
            g1 += h * whhT[i*128 + t];
            g2 += h * whhT[i*128 + t + 64];
        }
        gate[t] = g1; gate[t+64] = g2;
        __syncthreads();
        if (t < D) {
            float ig = sigf(gate[t]);
            float fg = sigf(gate[D+t]);
            float gg = tanhf(gate[2*D+t]);
            float og = sigf(gate[3*D+t]);
            float c  = fg*ccv[t] + ig*gg;
            ccv[t] = c;
            float h = og*tanhf(c);
            hhv[t] = h;
            qv[t]  = h;
        }
        __syncthreads();
        float e = -1e30f;
        if (t < cnt) {
            float s = 0.0f;
            #pragma unroll
            for (int o = 0; o < D; ++o) s += oL[t][o]*qv[o];
            e = s;
        }
        float mx = e;
        #pragma unroll
        for (int off = 32; off > 0; off >>= 1) mx = fmaxf(mx, __shfl_xor(mx, off, 64));
        float ex = (t < cnt) ? expf(e - mx) : 0.0f;
        float sm = ex;
        #pragma unroll
        for (int off = 32; off > 0; off >>= 1) sm += __shfl_xor(sm, off, 64);
        if (t < cnt) ea[t] = ex / sm;
        __syncthreads();
        if (t < D) {
            float acc = 0.0f;
            for (int i = 0; i < cnt; ++i) acc += ea[i]*oL[i][t];
            qs[t]   = qv[t];
            qs[D+t] = acc;
        }
        __syncthreads();
    }
    float ge1 = l1b[t], ge2 = l1b[t+64];
    #pragma unroll
    for (int i = 0; i < 2*D; ++i) {
        float q = qs[i];
        ge1 += q*l1T[i*128 + t];
        ge2 += q*l1T[i*128 + t + 64];
    }
    demb[(size_t)b*128 + t]      = ge1;
    demb[(size_t)b*128 + t + 64] = ge2;
    float p = fmaxf(ge1, 0.0f)*l2w[t] + fmaxf(ge2, 0.0f)*l2w[t+64];
    #pragma unroll
    for (int off = 32; off > 0; off >>= 1) p += __shfl_xor(p, off, 64);
    if (t == 0) dpred[b] = p + l2b[0];
}

extern "C" void kernel_launch(void* const* d_in, const int* in_sizes, int n_in,
                              void* d_out, int out_size, void* d_ws, size_t ws_size,
                              hipStream_t stream) {
    const float* x       = (const float*)d_in[0];
    const float* eattr   = (const float*)d_in[1];
    const float* lin0_w  = (const float*)d_in[2];
    const float* lin0_b  = (const float*)d_in[3];
    const float* enn_w1  = (const float*)d_in[4];
    const float* enn_b1  = (const float*)d_in[5];
    const float* enn_w2  = (const float*)d_in[6];
    const float* enn_b2  = (const float*)d_in[7];
    const float* root_w  = (const float*)d_in[8];
    const float* conv_b  = (const float*)d_in[9];
    const float* gru_wih = (const float*)d_in[10];
    const float* gru_whh = (const float*)d_in[11];
    const float* gru_bih = (const float*)d_in[12];
    const float* gru_bhh = (const float*)d_in[13];
    const float* lstm_wih= (const float*)d_in[14];
    const float* lstm_whh= (const float*)d_in[15];
    const float* lstm_bih= (const float*)d_in[16];
    const float* lstm_bhh= (const float*)d_in[17];
    const float* lin1_w  = (const float*)d_in[18];
    const float* lin1_b  = (const float*)d_in[19];
    const float* lin2_w  = (const float*)d_in[20];
    const float* lin2_b  = (const float*)d_in[21];
    const int*   eidx    = (const int*)d_in[22];

    int N = in_sizes[0]/FIN;     // 100000
    int E = in_sizes[1]/3;       // 300000
    int B = 4096;
    const int* src = eidx;
    const int* dst = eidx + E;
    int nte = (E + 31) / 32;     // 9375 (exact: E % 32 == 0)

    char* ws = (char*)d_ws;
    size_t off = 0;
    auto alloc = [&](size_t bytes)->void* {
        void* p = ws + off; off += (bytes + 255) & ~(size_t)255; return p;
    };
    float* outb  = (float*)alloc((size_t)N*D*sizeof(float));          // 12.8 MB
    float* agg   = (float*)alloc((size_t)N*D*sizeof(float));          // 12.8 MB
    float* invd  = (float*)alloc((size_t)N*sizeof(float));
    int*   deg   = (int*)  alloc((size_t)N*sizeof(int));
    float* wihT  = (float*)alloc((size_t)128*64*sizeof(float));
    float* whhT  = (float*)alloc((size_t)128*32*sizeof(float));
    float* l1T   = (float*)alloc((size_t)128*64*sizeof(float));
    short* ehidF = (short*)alloc((size_t)nte*NKT*64*8*sizeof(short)); // 86.4 MB
    short* w2F   = (short*)alloc((size_t)32*NKT*64*8*sizeof(short));  // 288 KB
    (void)ws_size; (void)n_in; (void)out_size;

    hipMemsetAsync(deg, 0, (size_t)N*sizeof(int), stream);
    hipMemsetAsync(agg, 0, (size_t)N*D*sizeof(float), stream);        // once; k_gru re-zeroes
    k_deg<<<(E+255)/256, 256, 0, stream>>>(dst, deg, E);
    k_invdeg<<<(N+255)/256, 256, 0, stream>>>(deg, invd, N);
    k_tposew<<<32, 256, 0, stream>>>(lstm_wih, lstm_whh, lin1_w, wihT, whhT, l1T);
    k_lin0<<<(N+7)/8, 256, 0, stream>>>(x, lin0_w, lin0_b, outb, N);
    k_ehidf<<<(nte*NKT*64+255)/256, 256, 0, stream>>>(eattr, enn_w1, enn_b1, ehidF, E, nte);
    k_w2f<<<(32*NKT*64+255)/256, 256, 0, stream>>>(enn_w2, enn_b2, w2F);

    for (int it = 0; it < 3; ++it) {
        k_fused<<<nte, 1024, 0, stream>>>(ehidF, w2F, outb, src, dst, agg);
        k_gru<<<1024, 256, 0, stream>>>(outb, agg, invd, root_w, conv_b,
                                        gru_wih, gru_whh, gru_bih, gru_bhh, N);
    }

    float* dpred = (float*)d_out;
    float* demb  = (float*)d_out + B;
    k_s2s<<<B, 64, 0, stream>>>(outb, wihT, whhT, lstm_bih, lstm_bhh,
                                l1T, lin1_b, lin2_w, lin2_b, dpred, demb, N, B);
}

// Round 19
// 760.187 us; speedup vs baseline: 1.9343x; 1.9343x over previous
//
#include <hip/hip_runtime.h>
#include <math.h>

#define D   32
#define FIN 16
#define KH  128
#define NW  1024
#define NKT 9          // 8 real K-tiles + 1 bias tile (K=144, ones-column ⊗ b2-row)
#define WEPITCH 1032   // shorts per WeL edge row (1024 + 8 pad)

typedef __attribute__((ext_vector_type(8)))  short short8;
typedef __attribute__((ext_vector_type(16))) float f32x16;

__device__ __forceinline__ float sigf(float x){ return 1.0f/(1.0f+expf(-x)); }
__device__ __forceinline__ short f2bf(float f){ __bf16 h = (__bf16)f; return __builtin_bit_cast(short, h); }
__device__ __forceinline__ float bf2f(short s){ return (float)__builtin_bit_cast(__bf16, s); }

// ---------------- degree / inv_deg ----------------
__global__ void k_deg(const int* __restrict__ dst, int* __restrict__ deg, int E){
    int e = blockIdx.x*256 + threadIdx.x;
    if (e < E) atomicAdd(&deg[dst[e]], 1);
}
__global__ void k_invdeg(const int* __restrict__ deg, float* __restrict__ invd, int n){
    int i = blockIdx.x*256 + threadIdx.x;
    if (i < n) { int d = deg[i]; invd[i] = (d > 0) ? (1.0f/(float)d) : 0.0f; }
}

// ---------------- transpose LSTM / lin1 weights ----------------
__global__ void k_tposew(const float* __restrict__ wih, const float* __restrict__ whh,
                         const float* __restrict__ l1w,
                         float* __restrict__ wihT, float* __restrict__ whhT,
                         float* __restrict__ l1T){
    int t = blockIdx.x*256 + threadIdx.x;
    if (t < 128*64) { int j = t/64, i = t%64; wihT[i*128+j] = wih[t]; l1T[i*128+j] = l1w[t]; }
    if (t < 128*32) { int j = t/32, i = t%32; whhT[i*128+j] = whh[t]; }
}

// ---------------- lin0 + relu (fp32) ----------------
__global__ __launch_bounds__(256) void k_lin0(const float* __restrict__ x,
    const float* __restrict__ w, const float* __restrict__ b,
    float* __restrict__ out, int n){
    __shared__ float wT[FIN*33];
    __shared__ float sb[D];
    int t = threadIdx.x;
    for (int idx = t; idx < D*FIN; idx += 256) {
        int o = idx/FIN, i = idx%FIN; wT[i*33+o] = w[idx];
    }
    if (t < D) sb[t] = b[t];
    __syncthreads();
    int g = t >> 5, o = t & 31;
    int node = blockIdx.x*8 + g;
    if (node >= n) return;
    float xo = (o < FIN) ? x[node*FIN + o] : 0.0f;
    float acc = sb[o];
    #pragma unroll
    for (int i = 0; i < FIN; ++i) {
        float xi = __shfl(xo, i, 32);
        acc += xi * wT[i*33+o];
    }
    out[node*D + o] = fmaxf(acc, 0.0f);
}

// ---------------- ehid in MFMA-fragment-major bf16, K extended to 144 ----------------
__global__ __launch_bounds__(256) void k_ehidf(const float* __restrict__ attr,
    const float* __restrict__ w1, const float* __restrict__ b1,
    short* __restrict__ ehidF, int E, int nte){
    int f = blockIdx.x*256 + threadIdx.x;
    if (f >= nte*NKT*64) return;
    int l = f & 63; int g = f >> 6; int kt = g % NKT; int te = g / NKT;
    int e = te*32 + (l & 31);
    int hi = l >> 5;
    short8 v;
    if (kt == 8) {
        #pragma unroll
        for (int j = 0; j < 8; ++j) v[j] = 0;
        if (hi == 0) v[0] = f2bf(1.0f);
    } else {
        int k0 = kt*16 + hi*8;
        float a0=0.f, a1=0.f, a2=0.f;
        if (e < E) { a0 = attr[(size_t)e*3]; a1 = attr[(size_t)e*3+1]; a2 = attr[(size_t)e*3+2]; }
        #pragma unroll
        for (int j = 0; j < 8; ++j) {
            int k = k0 + j;
            float t = b1[k] + a0*w1[k*3] + a1*w1[k*3+1] + a2*w1[k*3+2];
            v[j] = f2bf(fmaxf(t, 0.0f));
        }
    }
    *reinterpret_cast<short8*>(ehidF + (size_t)f*8) = v;
}

// ---------------- w2 in MFMA-fragment-major bf16 (B operand), K=144 ----------------
__global__ __launch_bounds__(256) void k_w2f(const float* __restrict__ w2,
    const float* __restrict__ b2, short* __restrict__ w2F){
    int f = blockIdx.x*256 + threadIdx.x;
    if (f >= 32*NKT*64) return;
    int l = f & 63; int g = f >> 6; int kt = g % NKT; int tn = g / NKT;
    int n = tn*32 + (l & 31);
    int hi = l >> 5;
    short8 v;
    if (kt == 8) {
        #pragma unroll
        for (int j = 0; j < 8; ++j) v[j] = 0;
        if (hi == 0) v[0] = f2bf(b2[n]);
    } else {
        int k0 = kt*16 + hi*8;
        #pragma unroll
        for (int j = 0; j < 8; ++j) v[j] = f2bf(w2[n*KH + k0 + j]);
    }
    *reinterpret_cast<short8*>(w2F + (size_t)f*8) = v;
}

// ---------------- fused NNConv (R4 structure, measured 178 us): MFMA -> bf16 WeL -> shfl msg ----
// Block = 32-edge tile, 16 waves. Wave w: mfma(A=ehfrag, B=w2frag(nt)), nt∈{2w,2w+1}
//   -> C[row=edge=(r&3)+8(r>>2)+4hi][col], n = nt*32+col. Store bf16 to WeL[edge][n].
// msg phase: wave w handles edges 2w+hi; lane col computes sum_i x[src][i]*WeL[edge][i*32+col]
// via 32x {shfl broadcast + ds_read_u16 + fma}; ONE atomic per (edge,o), half-wave coalesced.
// Bias b2 enters via the NKT=9 K-extension (ones-column ⊗ b2-row) — no epilogue add needed.
// Session lessons baked in: coalesced atomics are a first-class layout constraint; 1024-thr
// blocks cap at 64 VGPR (this kernel: 32, zero spill); occupancy 78% beats bigger tiles.
__global__ __launch_bounds__(1024) void k_fused(
    const short* __restrict__ ehidF, const short* __restrict__ w2F,
    const float* __restrict__ nodef,
    const int* __restrict__ src, const int* __restrict__ dst,
    float* __restrict__ agg){
    __shared__ short WeL[32*WEPITCH];     // 66048 B, pitch 1032 breaks bank alias
    int tid = threadIdx.x;
    int w = tid >> 6, l = tid & 63;
    int te = blockIdx.x;                  // E % 32 == 0
    int col = l & 31, hi = l >> 5;

    int nt0 = 2*w, nt1 = 2*w + 1;
    const short8* A8 = reinterpret_cast<const short8*>(ehidF) + (size_t)te*(NKT*64);
    const short8* B8 = reinterpret_cast<const short8*>(w2F);
    f32x16 acc0 = {}; f32x16 acc1 = {};
    #pragma unroll
    for (int kt = 0; kt < NKT; ++kt) {
        short8 a  = A8[kt*64 + l];
        short8 b0 = B8[(nt0*NKT + kt)*64 + l];
        short8 b1 = B8[(nt1*NKT + kt)*64 + l];
        acc0 = __builtin_amdgcn_mfma_f32_32x32x16_bf16(a, b0, acc0, 0, 0, 0);
        acc1 = __builtin_amdgcn_mfma_f32_32x32x16_bf16(a, b1, acc1, 0, 0, 0);
    }
    #pragma unroll
    for (int r = 0; r < 16; ++r) {
        int edge = (r & 3) + 8*(r >> 2) + 4*hi;
        WeL[edge*WEPITCH + nt0*32 + col] = f2bf(acc0[r]);
        WeL[edge*WEPITCH + nt1*32 + col] = f2bf(acc1[r]);
    }
    __syncthreads();

    // msg phase: edge eloc = 2w + hi, lane handles output o = col
    int eloc = 2*w + hi;
    int e = te*32 + eloc;
    int s = src[e];
    float vo = nodef[(size_t)s*D + col];
    float msg = 0.0f;
    const short* W = &WeL[eloc*WEPITCH];
    #pragma unroll
    for (int i = 0; i < D; ++i) {
        float vi = __shfl(vo, i, 32);
        msg += vi * bf2f(W[i*32 + col]);
    }
    atomicAdd(&agg[(size_t)dst[e]*D + col], msg);
}

// ---------------- scatter-mean finish + root + relu + GRU v2 (fp32, b128 LDS) ----
// Single-node form: 48 VGPR, zero spill. All batching variants (2-node R18, 4-node R15)
// cross the 128-VGPR spill cliff on this toolchain — this is the constrained optimum.
__global__ __launch_bounds__(256) void k_gru(float* __restrict__ out,
    float* __restrict__ agg, const float* __restrict__ invd,
    const float* __restrict__ root_w, const float* __restrict__ conv_b,
    const float* __restrict__ wih, const float* __restrict__ whh,
    const float* __restrict__ bih, const float* __restrict__ bhh, int n){
    __shared__ float swih[3][32][36];   // swih[c][o][i] = wih[(c*32+o)*32+i]
    __shared__ float swhh[3][32][36];
    __shared__ float srt[32][36];       // srt[o][i] = root_w[i*32+o]
    __shared__ float hL[8][32], mL[8][32];
    __shared__ float sbih[96], sbhh[96], scb[32];
    int t = threadIdx.x;
    for (int idx = t; idx < 96*32; idx += 256) {
        int j = idx >> 5, i = idx & 31; int c = j >> 5, o = j & 31;
        swih[c][o][i] = wih[idx];
        swhh[c][o][i] = whh[idx];
    }
    for (int idx = t; idx < 32*32; idx += 256) {
        int i = idx >> 5, o = idx & 31;
        srt[o][i] = root_w[idx];
    }
    if (t < 96) { sbih[t] = bih[t]; sbhh[t] = bhh[t]; }
    if (t < 32) scb[t] = conv_b[t];
    __syncthreads();

    int g = t >> 5, o = t & 31;
    int npass = (n + 7) / 8;
    for (int p = blockIdx.x; p < npass; p += gridDim.x) {
        int node = p*8 + g;
        if (node >= n) continue;
        float ho = out[(size_t)node*D + o];
        hL[g][o] = ho;
        float a = agg[(size_t)node*D + o];
        agg[(size_t)node*D + o] = 0.0f;               // pre-zero for next iteration
        float acc = a*invd[node] + scb[o];
        #pragma unroll
        for (int q = 0; q < 8; ++q) {
            float4 h4 = *reinterpret_cast<const float4*>(&hL[g][q*4]);   // uniform-addr broadcast
            float4 r4 = *reinterpret_cast<const float4*>(&srt[o][q*4]);
            acc += h4.x*r4.x + h4.y*r4.y + h4.z*r4.z + h4.w*r4.w;
        }
        float m = fmaxf(acc, 0.0f);
        mL[g][o] = m;
        float gi0 = sbih[o], gi1 = sbih[o+32], gi2 = sbih[o+64];
        float gh0 = sbhh[o], gh1 = sbhh[o+32], gh2 = sbhh[o+64];
        #pragma unroll
        for (int q = 0; q < 8; ++q) {
            float4 m4 = *reinterpret_cast<const float4*>(&mL[g][q*4]);
            float4 h4 = *reinterpret_cast<const float4*>(&hL[g][q*4]);
            float4 wa = *reinterpret_cast<const float4*>(&swih[0][o][q*4]);
            float4 wb = *reinterpret_cast<const float4*>(&swih[1][o][q*4]);
            float4 wc = *reinterpret_cast<const float4*>(&swih[2][o][q*4]);
            float4 va = *reinterpret_cast<const float4*>(&swhh[0][o][q*4]);
            float4 vb = *reinterpret_cast<const float4*>(&swhh[1][o][q*4]);
            float4 vc = *reinterpret_cast<const float4*>(&swhh[2][o][q*4]);
            gi0 += m4.x*wa.x + m4.y*wa.y + m4.z*wa.z + m4.w*wa.w;
            gi1 += m4.x*wb.x + m4.y*wb.y + m4.z*wb.z + m4.w*wb.w;
            gi2 += m4.x*wc.x + m4.y*wc.y + m4.z*wc.z + m4.w*wc.w;
            gh0 += h4.x*va.x + h4.y*va.y + h4.z*va.z + h4.w*va.w;
            gh1 += h4.x*vb.x + h4.y*vb.y + h4.z*vb.z + h4.w*vb.w;
            gh2 += h4.x*vc.x + h4.y*vc.y + h4.z*vc.z + h4.w*vc.w;
        }
        float r  = sigf(gi0+gh0);
        float z  = sigf(gi1+gh1);
        float ng = tanhf(gi2 + r*gh2);
        out[(size_t)node*D + o] = (1.0f - z)*ng + z*ho;
    }
}

// ---------------- Set2Set (3 steps) + lin1/lin2 readout (fp32, wave-parallel) ----------------
__global__ __launch_bounds__(64) void k_s2s(const float* __restrict__ out,
    const float* __restrict__ wihT, const float* __restrict__ whhT,
    const float* __restrict__ bih, const float* __restrict__ bhh,
    const float* __restrict__ l1T, const float* __restrict__ l1b,
    const float* __restrict__ l2w, const float* __restrict__ l2b,
    float* __restrict__ dpred, float* __restrict__ demb, int n, int ngr){
    int b = blockIdx.x, t = threadIdx.x;
    int start = (int)(((long long)b*n + ngr - 1)/ngr);
    int end   = (int)(((long long)(b+1)*n + ngr - 1)/ngr);
    if (end > n) end = n;
    int cnt = end - start;              // 24 or 25 here
    __shared__ float oL[32][33];
    __shared__ float qs[2*D];
    __shared__ float hhv[D], ccv[D], qv[D];
    __shared__ float gate[4*D];
    __shared__ float ea[32];
    for (int idx = t; idx < cnt*D; idx += 64) {
        int r = idx >> 5, o = idx & 31;
        oL[r][o] = out[(size_t)(start+r)*D + o];
    }
    if (t < 2*D) qs[t] = 0.0f;
    if (t < D) { hhv[t] = 0.0f; ccv[t] = 0.0f; }
    __syncthreads();
    for (int step = 0; step < 3; ++step) {
        float g1 = bih[t] + bhh[t];
        float g2 = bih[t+64] + bhh[t+64];
        #pragma unroll
        for (int i = 0; i < 2*D; ++i) {
            float q = qs[i];
            g1 += q * wihT[i*128 + t];
            g2 += q * wihT[i*128 + t + 64];
        }
        #pragma unroll
        for (int i = 0; i < D; ++i) {
            float h = hhv[i];
            g1 += h * whhT[i*128 + t];
            g2 += h * whhT[i*128 + t + 64];
        }
        gate[t] = g1; gate[t+64] = g2;
        __syncthreads();
        if (t < D) {
            float ig = sigf(gate[t]);
            float fg = sigf(gate[D+t]);
            float gg = tanhf(gate[2*D+t]);
            float og = sigf(gate[3*D+t]);
            float c  = fg*ccv[t] + ig*gg;
            ccv[t] = c;
            float h = og*tanhf(c);
            hhv[t] = h;
            qv[t]  = h;
        }
        __syncthreads();
        float e = -1e30f;
        if (t < cnt) {
            float s = 0.0f;
            #pragma unroll
            for (int o = 0; o < D; ++o) s += oL[t][o]*qv[o];
            e = s;
        }
        float mx = e;
        #pragma unroll
        for (int off = 32; off > 0; off >>= 1) mx = fmaxf(mx, __shfl_xor(mx, off, 64));
        float ex = (t < cnt) ? expf(e - mx) : 0.0f;
        float sm = ex;
        #pragma unroll
        for (int off = 32; off > 0; off >>= 1) sm += __shfl_xor(sm, off, 64);
        if (t < cnt) ea[t] = ex / sm;
        __syncthreads();
        if (t < D) {
            float acc = 0.0f;
            for (int i = 0; i < cnt; ++i) acc += ea[i]*oL[i][t];
            qs[t]   = qv[t];
            qs[D+t] = acc;
        }
        __syncthreads();
    }
    float ge1 = l1b[t], ge2 = l1b[t+64];
    #pragma unroll
    for (int i = 0; i < 2*D; ++i) {
        float q = qs[i];
        ge1 += q*l1T[i*128 + t];
        ge2 += q*l1T[i*128 + t + 64];
    }
    demb[(size_t)b*128 + t]      = ge1;
    demb[(size_t)b*128 + t + 64] = ge2;
    float p = fmaxf(ge1, 0.0f)*l2w[t] + fmaxf(ge2, 0.0f)*l2w[t+64];
    #pragma unroll
    for (int off = 32; off > 0; off >>= 1) p += __shfl_xor(p, off, 64);
    if (t == 0) dpred[b] = p + l2b[0];
}

extern "C" void kernel_launch(void* const* d_in, const int* in_sizes, int n_in,
                              void* d_out, int out_size, void* d_ws, size_t ws_size,
                              hipStream_t stream) {
    const float* x       = (const float*)d_in[0];
    const float* eattr   = (const float*)d_in[1];
    const float* lin0_w  = (const float*)d_in[2];
    const float* lin0_b  = (const float*)d_in[3];
    const float* enn_w1  = (const float*)d_in[4];
    const float* enn_b1  = (const float*)d_in[5];
    const float* enn_w2  = (const float*)d_in[6];
    const float* enn_b2  = (const float*)d_in[7];
    const float* root_w  = (const float*)d_in[8];
    const float* conv_b  = (const float*)d_in[9];
    const float* gru_wih = (const float*)d_in[10];
    const float* gru_whh = (const float*)d_in[11];
    const float* gru_bih = (const float*)d_in[12];
    const float* gru_bhh = (const float*)d_in[13];
    const float* lstm_wih= (const float*)d_in[14];
    const float* lstm_whh= (const float*)d_in[15];
    const float* lstm_bih= (const float*)d_in[16];
    const float* lstm_bhh= (const float*)d_in[17];
    const float* lin1_w  = (const float*)d_in[18];
    const float* lin1_b  = (const float*)d_in[19];
    const float* lin2_w  = (const float*)d_in[20];
    const float* lin2_b  = (const float*)d_in[21];
    const int*   eidx    = (const int*)d_in[22];

    int N = in_sizes[0]/FIN;     // 100000
    int E = in_sizes[1]/3;       // 300000
    int B = 4096;
    const int* src = eidx;
    const int* dst = eidx + E;
    int nte = (E + 31) / 32;     // 9375 (exact: E % 32 == 0)

    char* ws = (char*)d_ws;
    size_t off = 0;
    auto alloc = [&](size_t bytes)->void* {
        void* p = ws + off; off += (bytes + 255) & ~(size_t)255; return p;
    };
    float* outb  = (float*)alloc((size_t)N*D*sizeof(float));          // 12.8 MB
    float* agg   = (float*)alloc((size_t)N*D*sizeof(float));          // 12.8 MB
    float* invd  = (float*)alloc((size_t)N*sizeof(float));
    int*   deg   = (int*)  alloc((size_t)N*sizeof(int));
    float* wihT  = (float*)alloc((size_t)128*64*sizeof(float));
    float* whhT  = (float*)alloc((size_t)128*32*sizeof(float));
    float* l1T   = (float*)alloc((size_t)128*64*sizeof(float));
    short* ehidF = (short*)alloc((size_t)nte*NKT*64*8*sizeof(short)); // 86.4 MB
    short* w2F   = (short*)alloc((size_t)32*NKT*64*8*sizeof(short));  // 288 KB
    (void)ws_size; (void)n_in; (void)out_size;

    hipMemsetAsync(deg, 0, (size_t)N*sizeof(int), stream);
    hipMemsetAsync(agg, 0, (size_t)N*D*sizeof(float), stream);        // once; k_gru re-zeroes
    k_deg<<<(E+255)/256, 256, 0, stream>>>(dst, deg, E);
    k_invdeg<<<(N+255)/256, 256, 0, stream>>>(deg, invd, N);
    k_tposew<<<32, 256, 0, stream>>>(lstm_wih, lstm_whh, lin1_w, wihT, whhT, l1T);
    k_lin0<<<(N+7)/8, 256, 0, stream>>>(x, lin0_w, lin0_b, outb, N);
    k_ehidf<<<(nte*NKT*64+255)/256, 256, 0, stream>>>(eattr, enn_w1, enn_b1, ehidF, E, nte);
    k_w2f<<<(32*NKT*64+255)/256, 256, 0, stream>>>(enn_w2, enn_b2, w2F);

    for (int it = 0; it < 3; ++it) {
        k_fused<<<nte, 1024, 0, stream>>>(ehidF, w2F, outb, src, dst, agg);
        k_gru<<<1024, 256, 0, stream>>>(outb, agg, invd, root_w, conv_b,
                                        gru_wih, gru_whh, gru_bih, gru_bhh, N);
    }

    float* dpred = (float*)d_out;
    float* demb  = (float*)d_out + B;
    k_s2s<<<B, 64, 0, stream>>>(outb, wihT, whhT, lstm_bih, lstm_bhh,
                                l1T, lin1_b, lin2_w, lin2_b, dpred, demb, N, B);
}